// Round 1
// baseline (89.684 us; speedup 1.0000x reference)
//
#include <hip/hip_runtime.h>

// ConvTransduce1D: B=16, T=4096, C=128, K=5, stride=1, pad=2, W=4096, Kn=52.
// Only channels 0..27 are used (blank=0, chars 1..26, bigram second chars 2..27).
// Linear-domain CTC forward: p_state' built from exp(emission) products.
// out[b][w][k], k in [0,52): k=c-1 for single-char token c (1..26),
//                            k=24+cB for bigram (cB-1, cB), cB in 2..27.

constexpr int TFRM  = 4096;   // T
constexpr int CCH   = 128;    // C
constexpr int WN    = 4096;   // W
constexpr int KN    = 52;
constexpr int BB    = 16;

constexpr int WTILE  = 64;          // windows per block
constexpr int NTH    = 256;         // 64 windows x 4 worker threads
constexpr int FRAMES = WTILE + 4;   // 68 staged frames (w0-2 .. w0+WTILE+1)
constexpr int CH     = 28;          // staged channels
constexpr int LDSTR  = 29;          // padded LDS row stride (odd -> conflict-free)

__global__ __launch_bounds__(NTH)
void conv_transduce_kernel(const float* __restrict__ x, float* __restrict__ out) {
    __shared__ float E[FRAMES * LDSTR];

    const int b  = blockIdx.y;
    const int w0 = blockIdx.x * WTILE;

    // ---- stage exp(x[b, w0-2 .. w0+WTILE+1, 0:28]) into LDS ----
    for (int i = threadIdx.x; i < FRAMES * CH; i += NTH) {
        const int f  = i / CH;
        const int ch = i - f * CH;
        const int g  = w0 + f - 2;              // global frame (can be padded)
        float v = 0.0f;
        if (g >= 0 && g < TFRM)
            v = x[(size_t)(b * TFRM + g) * CCH + ch];
        E[f * LDSTR + ch] = __expf(v);          // padded frames -> exp(0)=1
    }
    __syncthreads();

    const int wl = threadIdx.x & 63;   // window within tile (wave = 64 consecutive windows)
    const int p  = threadIdx.x >> 6;   // worker 0..3, uniform per wave
    const int w  = w0 + wl;

    float E0[5];
    #pragma unroll
    for (int t = 0; t < 5; ++t) E0[t] = E[(wl + t) * LDSTR + 0];

    float* __restrict__ orow = out + (size_t)(b * WN + w) * KN;

    for (int j = p; j < 27; j += 4) {
        const int c = j + 1;           // channel of this iteration (1..27)
        float Ec[5];
        #pragma unroll
        for (int t = 0; t < 5; ++t) Ec[t] = E[(wl + t) * LDSTR + c];

        if (c <= 26) {
            // single-char token c: states 0..2
            // a0' = a0*E0 ; a1' = (a0+a1)*Ec ; a2' = (a1+a2)*E0 ; out = log(a1+a2)
            float p0 = 1.0f, p1 = 0.0f, p2 = 0.0f;
            #pragma unroll
            for (int t = 0; t < 5; ++t) {
                const float n0 = p0 * E0[t];
                const float n1 = (p0 + p1) * Ec[t];
                const float n2 = (p1 + p2) * E0[t];
                p0 = n0; p1 = n1; p2 = n2;
            }
            orow[c - 1] = __logf(p1 + p2);
        }
        if (c >= 2) {
            // bigram token (c-1, c): states 0..4, skip arc (1,3,c)
            float Ea[5];
            #pragma unroll
            for (int t = 0; t < 5; ++t) Ea[t] = E[(wl + t) * LDSTR + (c - 1)];
            float q0 = 1.0f, q1 = 0.0f, q2 = 0.0f, q3 = 0.0f, q4 = 0.0f;
            #pragma unroll
            for (int t = 0; t < 5; ++t) {
                const float s01 = q0 + q1;
                const float s12 = q1 + q2;
                const float n0 = q0 * E0[t];
                const float n1 = s01 * Ea[t];
                const float n2 = s12 * E0[t];
                const float n3 = (s12 + q3) * Ec[t];
                const float n4 = (q3 + q4) * E0[t];
                q0 = n0; q1 = n1; q2 = n2; q3 = n3; q4 = n4;
            }
            orow[24 + c] = __logf(q3 + q4);
        }
    }
}

extern "C" void kernel_launch(void* const* d_in, const int* in_sizes, int n_in,
                              void* d_out, int out_size, void* d_ws, size_t ws_size,
                              hipStream_t stream) {
    (void)in_sizes; (void)n_in; (void)d_ws; (void)ws_size; (void)out_size;
    const float* x = (const float*)d_in[0];
    float* out = (float*)d_out;
    dim3 grid(WN / WTILE, BB);   // 64 x 16 = 1024 blocks
    conv_transduce_kernel<<<grid, NTH, 0, stream>>>(x, out);
}

// Round 3
// 77.662 us; speedup vs baseline: 1.1548x; 1.1548x over previous
//
#include <hip/hip_runtime.h>

// ConvTransduce1D: B=16, T=4096, C=128, K=5, stride=1, pad=2, W=4096, Kn=52.
// Only channels 0..27 are used (blank=0, chars 1..26, bigram second chars 2..27).
// Linear-domain CTC forward. Key fusion: bigram (a,a+1) states 0..2 ARE the
// single-token-a states, so one 5-state recurrence yields both outputs:
//   out[a-1]  = log(q1+q2)   (single token a)
//   out[25+a] = log(q3+q4)   (bigram (a, a+1))

constexpr int TFRM  = 4096;   // T
constexpr int CCH   = 128;    // C
constexpr int WN    = 4096;   // W
constexpr int KN    = 52;
constexpr int BB    = 16;

constexpr int WTILE  = 64;          // windows per block
constexpr int NTH    = 256;         // 64 windows x 4 worker waves
constexpr int FRAMES = WTILE + 4;   // 68 staged frames (w0-2 .. w0+WTILE+1)
constexpr int LDSTR  = 29;          // padded E row stride (odd -> conflict-free)
constexpr int OSTR   = 53;          // padded O row stride (odd -> conflict-free)

__global__ __launch_bounds__(NTH)
void conv_transduce_kernel(const float* __restrict__ x, float* __restrict__ out) {
    __shared__ float E[FRAMES * LDSTR];   // exp(emissions), ch 0..27
    __shared__ float O[WTILE * OSTR];     // per-window outputs, k 0..51

    const int b  = blockIdx.y;
    const int w0 = blockIdx.x * WTILE;

    // ---- stage exp(x[b, w0-2 .. w0+65, 0:28]) into LDS, float4 loads ----
    for (int i = threadIdx.x; i < FRAMES * 7; i += NTH) {
        const int f = i / 7;
        const int v = i - f * 7;              // float4 index 0..6 (ch 4v..4v+3)
        const int g = w0 + f - 2;
        float* dst = &E[f * LDSTR + v * 4];
        if (g >= 0 && g < TFRM) {
            const float4 val = *reinterpret_cast<const float4*>(
                x + (size_t)(b * TFRM + g) * CCH + v * 4);
            dst[0] = __expf(val.x);
            dst[1] = __expf(val.y);
            dst[2] = __expf(val.z);
            dst[3] = __expf(val.w);
        } else {                              // zero-padded frame: exp(0)=1
            dst[0] = 1.0f; dst[1] = 1.0f; dst[2] = 1.0f; dst[3] = 1.0f;
        }
    }
    __syncthreads();

    const int wl = threadIdx.x & 63;   // window within tile (lane)
    const int p  = threadIdx.x >> 6;   // worker wave 0..3

    float E0[5];
    #pragma unroll
    for (int t = 0; t < 5; ++t) E0[t] = E[(wl + t) * LDSTR + 0];

    // fused recurrence: token a (1..26) + bigram (a, a+1)
    for (int a = p + 1; a <= 26; a += 4) {
        float Ea[5], Eb[5];
        #pragma unroll
        for (int t = 0; t < 5; ++t) Ea[t] = E[(wl + t) * LDSTR + a];
        #pragma unroll
        for (int t = 0; t < 5; ++t) Eb[t] = E[(wl + t) * LDSTR + a + 1];

        float q0 = 1.0f, q1 = 0.0f, q2 = 0.0f, q3 = 0.0f, q4 = 0.0f;
        #pragma unroll
        for (int t = 0; t < 5; ++t) {
            const float s01 = q0 + q1;
            const float s12 = q1 + q2;
            const float n0 = q0 * E0[t];
            const float n1 = s01 * Ea[t];
            const float n2 = s12 * E0[t];
            const float n3 = (s12 + q3) * Eb[t];   // skip arc (1,3) + (2,3) + self
            const float n4 = (q3 + q4) * E0[t];
            q0 = n0; q1 = n1; q2 = n2; q3 = n3; q4 = n4;
        }
        O[wl * OSTR + (a - 1)]  = __logf(q1 + q2);  // single-char token a
        O[wl * OSTR + (25 + a)] = __logf(q3 + q4);  // bigram (a, a+1)
    }
    __syncthreads();

    // ---- coalesced contiguous block write: 64 windows x 52 floats ----
    float* __restrict__ oblk = out + ((size_t)b * WN + w0) * KN;
    for (int i = threadIdx.x; i < WTILE * KN; i += NTH) {
        const int wi = i / KN;
        const int k  = i - wi * KN;
        oblk[i] = O[wi * OSTR + k];
    }
}

extern "C" void kernel_launch(void* const* d_in, const int* in_sizes, int n_in,
                              void* d_out, int out_size, void* d_ws, size_t ws_size,
                              hipStream_t stream) {
    (void)in_sizes; (void)n_in; (void)d_ws; (void)ws_size; (void)out_size;
    const float* x = (const float*)d_in[0];
    float* out = (float*)d_out;
    dim3 grid(WN / WTILE, BB);   // 64 x 16 = 1024 blocks
    conv_transduce_kernel<<<grid, NTH, 0, stream>>>(x, out);
}

// Round 4
// 76.755 us; speedup vs baseline: 1.1684x; 1.0118x over previous
//
#include <hip/hip_runtime.h>

// ConvTransduce1D: B=16, T=4096, C=128, K=5, stride=1, pad=2, W=4096, Kn=52.
// Only channels 0..27 are used (blank=0, chars 1..26, bigram second chars 2..27).
// Linear-domain CTC forward. Fusion: bigram (a,a+1) states 0..2 ARE the
// single-token-a states, so one 5-state recurrence yields both outputs:
//   out[a-1]  = log(q1+q2)   (single token a)
//   out[25+a] = log(q3+q4)   (bigram (a, a+1))

constexpr int TFRM  = 4096;   // T
constexpr int CCH   = 128;    // C
constexpr int WN    = 4096;   // W
constexpr int KN    = 52;
constexpr int BB    = 16;

constexpr int WTILE  = 32;          // windows per block
constexpr int NTH    = 128;         // 32 windows x 4 worker groups (2 waves)
constexpr int FRAMES = WTILE + 4;   // 36 staged frames (w0-2 .. w0+WTILE+1)
constexpr int LDSTR  = 29;          // padded E row stride (odd -> conflict-free)
constexpr int OSTR   = 53;          // padded O row stride (odd -> conflict-free)

__global__ __launch_bounds__(NTH)
void conv_transduce_kernel(const float* __restrict__ x, float* __restrict__ out) {
    __shared__ float E[FRAMES * LDSTR];   // exp(emissions), ch 0..27
    __shared__ float O[WTILE * OSTR];     // per-window outputs, k 0..51

    const int b  = blockIdx.y;
    const int w0 = blockIdx.x * WTILE;

    // ---- stage exp(x[b, w0-2 .. w0+33, 0:28]) into LDS, float4 loads ----
    for (int i = threadIdx.x; i < FRAMES * 7; i += NTH) {
        const int f = i / 7;
        const int v = i - f * 7;              // float4 index 0..6 (ch 4v..4v+3)
        const int g = w0 + f - 2;
        float* dst = &E[f * LDSTR + v * 4];
        if (g >= 0 && g < TFRM) {
            const float4 val = *reinterpret_cast<const float4*>(
                x + (size_t)(b * TFRM + g) * CCH + v * 4);
            dst[0] = __expf(val.x);
            dst[1] = __expf(val.y);
            dst[2] = __expf(val.z);
            dst[3] = __expf(val.w);
        } else {                              // zero-padded frame: exp(0)=1
            dst[0] = 1.0f; dst[1] = 1.0f; dst[2] = 1.0f; dst[3] = 1.0f;
        }
    }
    __syncthreads();

    const int wl = threadIdx.x & (WTILE - 1);   // window within tile
    const int p  = threadIdx.x / WTILE;         // worker 0..3 (half-wave uniform;
                                                // trip counts pair up 7/7 and 6/6)

    float E0[5];
    #pragma unroll
    for (int t = 0; t < 5; ++t) E0[t] = E[(wl + t) * LDSTR + 0];

    // fused recurrence: token a (1..26) + bigram (a, a+1)
    for (int a = p + 1; a <= 26; a += 4) {
        float Ea[5], Eb[5];
        #pragma unroll
        for (int t = 0; t < 5; ++t) Ea[t] = E[(wl + t) * LDSTR + a];
        #pragma unroll
        for (int t = 0; t < 5; ++t) Eb[t] = E[(wl + t) * LDSTR + a + 1];

        float q0 = 1.0f, q1 = 0.0f, q2 = 0.0f, q3 = 0.0f, q4 = 0.0f;
        #pragma unroll
        for (int t = 0; t < 5; ++t) {
            const float s01 = q0 + q1;
            const float s12 = q1 + q2;
            const float n0 = q0 * E0[t];
            const float n1 = s01 * Ea[t];
            const float n2 = s12 * E0[t];
            const float n3 = (s12 + q3) * Eb[t];   // skip (1,3) + (2,3) + self
            const float n4 = (q3 + q4) * E0[t];
            q0 = n0; q1 = n1; q2 = n2; q3 = n3; q4 = n4;
        }
        O[wl * OSTR + (a - 1)]  = __logf(q1 + q2);  // single-char token a
        O[wl * OSTR + (25 + a)] = __logf(q3 + q4);  // bigram (a, a+1)
    }
    __syncthreads();

    // ---- coalesced float4 block write: 32 windows x 13 float4 each ----
    // KN=52 is a multiple of 4 and oblk is 16B-aligned (208B rows).
    float* __restrict__ oblk = out + ((size_t)b * WN + w0) * KN;
    constexpr int NV4 = WTILE * (KN / 4);   // 416 float4s
    for (int j = threadIdx.x; j < NV4; j += NTH) {
        const int wi = j / (KN / 4);
        const int k4 = j - wi * (KN / 4);
        float4 v;
        const float* src = &O[wi * OSTR + k4 * 4];
        v.x = src[0]; v.y = src[1]; v.z = src[2]; v.w = src[3];
        *reinterpret_cast<float4*>(oblk + j * 4) = v;
    }
}

extern "C" void kernel_launch(void* const* d_in, const int* in_sizes, int n_in,
                              void* d_out, int out_size, void* d_ws, size_t ws_size,
                              hipStream_t stream) {
    (void)in_sizes; (void)n_in; (void)d_ws; (void)ws_size; (void)out_size;
    const float* x = (const float*)d_in[0];
    float* out = (float*)d_out;
    dim3 grid(WN / WTILE, BB);   // 128 x 16 = 2048 blocks (8/CU)
    conv_transduce_kernel<<<grid, NTH, 0, stream>>>(x, out);
}